// Round 1
// baseline (1860.002 us; speedup 1.0000x reference)
//
#include <hip/hip_runtime.h>
#include <hip/hip_bf16.h>

// CSPNet fused forward, MI355X. One workgroup per graph (G=512, A=24).
// Edge list is deterministic (fully-connected per graph): edge eg = i*24+j,
// e0=i, e1=j. ein@We1 is decomposed: h[i]@W1a + h[j]@W1b + lat@W1c + pe@W1d,
// so the 576-row edge GEMM only has the K=60 pe part + a K=128 second layer.

#define NG 512
#define NA 24
#define HID 128
#define TDIM 256
#define NBB 64
#define DIS 60
#define NLAYER 4
#define TPB 256
#define EDGE_IN 322

__device__ __forceinline__ float silu_f(float x) {
    return x / (1.0f + __expf(-x));
}

__device__ __forceinline__ float4 ld4(const float* __restrict__ p) {
    return *reinterpret_cast<const float4*>(p);
}

#define FMA4(ACC, S, W) { (ACC).x += (S)*(W).x; (ACC).y += (S)*(W).y; \
                          (ACC).z += (S)*(W).z; (ACC).w += (S)*(W).w; }

__global__ void __launch_bounds__(TPB, 2) cspnet_fused(
    const float* __restrict__ t_in,      // [G,256]
    const float* __restrict__ bb_embs,   // [N,64]
    const float* __restrict__ frac,      // [N,3]
    const float* __restrict__ so3,       // [N,16]
    const float* __restrict__ lattices,  // [G,6]
    const float* __restrict__ W_emb,     // [64,128]
    const float* __restrict__ b_emb,     // [128]
    const float* __restrict__ W_lat,     // [400,128]
    const float* __restrict__ b_lat,     // [128]
    const float* __restrict__ We1,       // [4,322,128]
    const float* __restrict__ be1,       // [4,128]
    const float* __restrict__ We2,       // [4,128,128]
    const float* __restrict__ be2,       // [4,128]
    const float* __restrict__ Wn1,       // [4,256,128]
    const float* __restrict__ bn1,       // [4,128]
    const float* __restrict__ Wn2,       // [4,128,128]
    const float* __restrict__ bn2,       // [4,128]
    const float* __restrict__ W_coord,   // [128,3]
    const float* __restrict__ W_lattice, // [128,6]
    const float* __restrict__ W_so3,     // [128,4]
    float* __restrict__ out)             // [512*6 | 12288*3 | 12288*4]
{
    const int g   = blockIdx.x;
    const int tid = threadIdx.x;
    const int cg  = tid & 31;   // channel group: c = 4*cg+q
    const int rg  = tid >> 5;   // row group: rows rg, rg+8, rg+16
    const int c0  = cg * 4;

    __shared__ float h_s[NA][HID];        // 12 KB
    __shared__ float hA_s[NA][HID];       // 12 KB (also emb scratch)
    __shared__ float hB_s[NA][HID];       // 12 KB (also node-mid scratch)
    __shared__ float agg_s[NA][HID];      // 12 KB
    __shared__ float latc_s[HID];
    __shared__ float tl_s[HID];           // t@W_lat part; reused as gfeat
    __shared__ float pe_s[NA][DIS];       // 5.6 KB
    __shared__ __hip_bfloat16 mid_s[NA][HID]; // 6 KB
    __shared__ float frac_s[NA][3];
    __shared__ float lat6_s[6];

    const float inv24 = 1.0f / 24.0f;

    // ---------------- prologue ----------------
    if (tid < NA * 3) {
        int i = tid / 3, d = tid - i * 3;
        frac_s[i][d] = frac[(size_t)(g * NA + i) * 3 + d];
    }
    if (tid < 6) lat6_s[tid] = lattices[(size_t)g * 6 + tid];

    // emb = bb @ W_emb + b_emb  -> hA_s
    {
        float4 acc[3];
        float4 be = ld4(b_emb + c0);
        acc[0] = be; acc[1] = be; acc[2] = be;
        const float* bbg = bb_embs + (size_t)(g * NA) * NBB;
        #pragma unroll 4
        for (int k = 0; k < NBB; ++k) {
            float4 w = ld4(W_emb + (size_t)k * HID + c0);
            float b0v = bbg[(rg     ) * NBB + k];
            float b1v = bbg[(rg +  8) * NBB + k];
            float b2v = bbg[(rg + 16) * NBB + k];
            FMA4(acc[0], b0v, w); FMA4(acc[1], b1v, w); FMA4(acc[2], b2v, w);
        }
        #pragma unroll
        for (int s = 0; s < 3; ++s)
            *reinterpret_cast<float4*>(&hA_s[rg + 8 * s][c0]) = acc[s];
    }

    // tl[c] = sum_k t[g][k] * W_lat[144+k][c]
    if (tid < HID) {
        float acc = 0.f;
        const float* tg = t_in + (size_t)g * TDIM;
        for (int k = 0; k < TDIM; ++k)
            acc += tg[k] * W_lat[(size_t)(144 + k) * HID + tid];
        tl_s[tid] = acc;
    }
    __syncthreads();

    // h = [emb | so3] @ W_lat[0:144] + tl + b_lat   (no activation)
    {
        float4 acc[3];
        float4 bl = ld4(b_lat + c0);
        float4 tv = *reinterpret_cast<const float4*>(tl_s + c0);
        bl.x += tv.x; bl.y += tv.y; bl.z += tv.z; bl.w += tv.w;
        acc[0] = bl; acc[1] = bl; acc[2] = bl;
        #pragma unroll 4
        for (int k = 0; k < HID; ++k) {
            float4 w = ld4(W_lat + (size_t)k * HID + c0);
            float e0v = hA_s[rg][k], e1v = hA_s[rg + 8][k], e2v = hA_s[rg + 16][k];
            FMA4(acc[0], e0v, w); FMA4(acc[1], e1v, w); FMA4(acc[2], e2v, w);
        }
        const float* so3g = so3 + (size_t)(g * NA) * 16;
        #pragma unroll
        for (int k = 0; k < 16; ++k) {
            float4 w = ld4(W_lat + (size_t)(HID + k) * HID + c0);
            float s0 = so3g[(rg     ) * 16 + k];
            float s1 = so3g[(rg +  8) * 16 + k];
            float s2 = so3g[(rg + 16) * 16 + k];
            FMA4(acc[0], s0, w); FMA4(acc[1], s1, w); FMA4(acc[2], s2, w);
        }
        #pragma unroll
        for (int s = 0; s < 3; ++s)
            *reinterpret_cast<float4*>(&h_s[rg + 8 * s][c0]) = acc[s];
    }
    __syncthreads();

    // ---------------- layers ----------------
    for (int l = 0; l < NLAYER; ++l) {
        const float* We1_l = We1 + (size_t)l * EDGE_IN * HID;
        const float* be1_l = be1 + l * HID;
        const float* We2_l = We2 + (size_t)l * HID * HID;
        const float* be2_l = be2 + l * HID;
        const float* Wn1_l = Wn1 + (size_t)l * 2 * HID * HID;
        const float* bn1_l = bn1 + l * HID;
        const float* Wn2_l = Wn2 + (size_t)l * HID * HID;
        const float* bn2_l = bn2 + l * HID;

        // phase 1: hA = h@We1[0:128], hB = h@We1[128:256]
        {
            float4 a[3], b[3];
            #pragma unroll
            for (int s = 0; s < 3; ++s) {
                a[s] = make_float4(0.f, 0.f, 0.f, 0.f);
                b[s] = make_float4(0.f, 0.f, 0.f, 0.f);
            }
            #pragma unroll 2
            for (int k = 0; k < HID; ++k) {
                float4 wa = ld4(We1_l + (size_t)k * HID + c0);
                float4 wb = ld4(We1_l + (size_t)(HID + k) * HID + c0);
                float h0v = h_s[rg][k], h1v = h_s[rg + 8][k], h2v = h_s[rg + 16][k];
                FMA4(a[0], h0v, wa); FMA4(a[1], h1v, wa); FMA4(a[2], h2v, wa);
                FMA4(b[0], h0v, wb); FMA4(b[1], h1v, wb); FMA4(b[2], h2v, wb);
            }
            #pragma unroll
            for (int s = 0; s < 3; ++s) {
                *reinterpret_cast<float4*>(&hA_s[rg + 8 * s][c0]) = a[s];
                *reinterpret_cast<float4*>(&hB_s[rg + 8 * s][c0]) = b[s];
            }
        }
        // latc = lat@We1[256:262] + be1
        if (tid < HID) {
            float acc = be1_l[tid];
            #pragma unroll
            for (int k = 0; k < 6; ++k)
                acc += lat6_s[k] * We1_l[(size_t)(2 * HID + k) * HID + tid];
            latc_s[tid] = acc;
        }
        // zero agg
        for (int v = tid; v < NA * HID; v += TPB)
            (&agg_s[0][0])[v] = 0.f;
        __syncthreads();

        // edge steps: one source node i0 per step (24 j-edges)
        for (int i0 = 0; i0 < NA; ++i0) {
            // pe[j][k]; k<30: sin(fd[d]*2pi*f), k>=30: cos; k2=k%30, d=k2/10, f=k2%10
            for (int v = tid; v < NA * DIS; v += TPB) {
                int e  = v / DIS;
                int k  = v - e * DIS;
                int k2 = (k < 30) ? k : k - 30;
                int d  = k2 / 10;
                int f  = k2 - d * 10;
                float fdv = frac_s[e][d] - frac_s[i0][d];
                fdv -= floorf(fdv);
                float ang = fdv * (6.283185307179586f * (float)f);
                pe_s[e][k] = (k < 30) ? sinf(ang) : cosf(ang);
            }
            __syncthreads();

            // mid[j][c] = silu(hA[i0][c] + hB[j][c] + latc[c] + pe[j]@W1d)
            {
                float4 acc[3];
                float4 lc = *reinterpret_cast<const float4*>(latc_s + c0);
                float4 ha = *reinterpret_cast<const float4*>(&hA_s[i0][c0]);
                lc.x += ha.x; lc.y += ha.y; lc.z += ha.z; lc.w += ha.w;
                #pragma unroll
                for (int s = 0; s < 3; ++s) {
                    float4 hb = *reinterpret_cast<const float4*>(&hB_s[rg + 8 * s][c0]);
                    acc[s].x = lc.x + hb.x; acc[s].y = lc.y + hb.y;
                    acc[s].z = lc.z + hb.z; acc[s].w = lc.w + hb.w;
                }
                #pragma unroll 4
                for (int k = 0; k < DIS; ++k) {
                    float4 w = ld4(We1_l + (size_t)(262 + k) * HID + c0);
                    float p0 = pe_s[rg][k], p1 = pe_s[rg + 8][k], p2 = pe_s[rg + 16][k];
                    FMA4(acc[0], p0, w); FMA4(acc[1], p1, w); FMA4(acc[2], p2, w);
                }
                #pragma unroll
                for (int s = 0; s < 3; ++s) {
                    int row = rg + 8 * s;
                    mid_s[row][c0 + 0] = __float2bfloat16(silu_f(acc[s].x));
                    mid_s[row][c0 + 1] = __float2bfloat16(silu_f(acc[s].y));
                    mid_s[row][c0 + 2] = __float2bfloat16(silu_f(acc[s].z));
                    mid_s[row][c0 + 3] = __float2bfloat16(silu_f(acc[s].w));
                }
            }
            __syncthreads();

            // ef[j][c] = silu(mid[j]@We2 + be2); agg[i0][c] += sum_j ef
            {
                float4 acc[3];
                float4 b2v = ld4(be2_l + c0);
                acc[0] = b2v; acc[1] = b2v; acc[2] = b2v;
                #pragma unroll 4
                for (int k = 0; k < HID; ++k) {
                    float4 w = ld4(We2_l + (size_t)k * HID + c0);
                    float m0 = __bfloat162float(mid_s[rg][k]);
                    float m1 = __bfloat162float(mid_s[rg + 8][k]);
                    float m2 = __bfloat162float(mid_s[rg + 16][k]);
                    FMA4(acc[0], m0, w); FMA4(acc[1], m1, w); FMA4(acc[2], m2, w);
                }
                float sx = silu_f(acc[0].x) + silu_f(acc[1].x) + silu_f(acc[2].x);
                float sy = silu_f(acc[0].y) + silu_f(acc[1].y) + silu_f(acc[2].y);
                float sz = silu_f(acc[0].z) + silu_f(acc[1].z) + silu_f(acc[2].z);
                float sw = silu_f(acc[0].w) + silu_f(acc[1].w) + silu_f(acc[2].w);
                atomicAdd(&agg_s[i0][c0 + 0], sx);
                atomicAdd(&agg_s[i0][c0 + 1], sy);
                atomicAdd(&agg_s[i0][c0 + 2], sz);
                atomicAdd(&agg_s[i0][c0 + 3], sw);
            }
            // no barrier: next pe writes pe_s (readers of pe_s all passed the
            // mid->ef barrier); next mid is fenced by next pe->mid barrier.
        }
        __syncthreads();   // all agg atomics done; hA/hB now dead

        // node MLP 1: hB = silu(h@Wn1[0:128] + (agg/24)@Wn1[128:256] + bn1)
        {
            float4 acc[3];
            float4 bv = ld4(bn1_l + c0);
            acc[0] = bv; acc[1] = bv; acc[2] = bv;
            #pragma unroll 2
            for (int k = 0; k < HID; ++k) {
                float4 w1 = ld4(Wn1_l + (size_t)k * HID + c0);
                float4 w2 = ld4(Wn1_l + (size_t)(HID + k) * HID + c0);
                float h0v = h_s[rg][k], h1v = h_s[rg + 8][k], h2v = h_s[rg + 16][k];
                float a0v = agg_s[rg][k] * inv24;
                float a1v = agg_s[rg + 8][k] * inv24;
                float a2v = agg_s[rg + 16][k] * inv24;
                FMA4(acc[0], h0v, w1); FMA4(acc[1], h1v, w1); FMA4(acc[2], h2v, w1);
                FMA4(acc[0], a0v, w2); FMA4(acc[1], a1v, w2); FMA4(acc[2], a2v, w2);
            }
            #pragma unroll
            for (int s = 0; s < 3; ++s) {
                float4 o;
                o.x = silu_f(acc[s].x); o.y = silu_f(acc[s].y);
                o.z = silu_f(acc[s].z); o.w = silu_f(acc[s].w);
                *reinterpret_cast<float4*>(&hB_s[rg + 8 * s][c0]) = o;
            }
        }
        __syncthreads();

        // node MLP 2 + residual: h += silu(hB@Wn2 + bn2)
        {
            float4 acc[3];
            float4 bv = ld4(bn2_l + c0);
            acc[0] = bv; acc[1] = bv; acc[2] = bv;
            #pragma unroll 2
            for (int k = 0; k < HID; ++k) {
                float4 w = ld4(Wn2_l + (size_t)k * HID + c0);
                float m0 = hB_s[rg][k], m1 = hB_s[rg + 8][k], m2 = hB_s[rg + 16][k];
                FMA4(acc[0], m0, w); FMA4(acc[1], m1, w); FMA4(acc[2], m2, w);
            }
            #pragma unroll
            for (int s = 0; s < 3; ++s) {
                int row = rg + 8 * s;
                float4 hv = *reinterpret_cast<const float4*>(&h_s[row][c0]);
                hv.x += silu_f(acc[s].x); hv.y += silu_f(acc[s].y);
                hv.z += silu_f(acc[s].z); hv.w += silu_f(acc[s].w);
                *reinterpret_cast<float4*>(&h_s[row][c0]) = hv;
            }
        }
        __syncthreads();
    }

    // ---------------- epilogue ----------------
    // gfeat (into tl_s), coord head, so3 head
    if (tid < HID) {
        float s = 0.f;
        #pragma unroll 4
        for (int i = 0; i < NA; ++i) s += h_s[i][tid];
        tl_s[tid] = s * inv24;
    }
    if (tid < NA * 3) {
        int i = tid / 3, d = tid - i * 3;
        float acc = 0.f;
        #pragma unroll 4
        for (int k = 0; k < HID; ++k) acc += h_s[i][k] * W_coord[k * 3 + d];
        acc += frac_s[i][d];
        acc -= floorf(acc);
        out[(size_t)NG * 6 + (size_t)(g * NA + i) * 3 + d] = acc;
    }
    if (tid < NA) {
        int i = tid;
        float v0 = 0.f, v1 = 0.f, v2 = 0.f, v3 = 0.f;
        #pragma unroll 4
        for (int k = 0; k < HID; ++k) {
            float hv = h_s[i][k];
            v0 += hv * W_so3[k * 4 + 0]; v1 += hv * W_so3[k * 4 + 1];
            v2 += hv * W_so3[k * 4 + 2]; v3 += hv * W_so3[k * 4 + 3];
        }
        float inv = 1.0f / sqrtf(v0 * v0 + v1 * v1 + v2 * v2 + v3 * v3);
        size_t o = (size_t)NG * 6 + (size_t)NG * NA * 3 + (size_t)(g * NA + i) * 4;
        out[o + 0] = v0 * inv; out[o + 1] = v1 * inv;
        out[o + 2] = v2 * inv; out[o + 3] = v3 * inv;
    }
    __syncthreads();
    if (tid < 6) {
        float acc = 0.f;
        #pragma unroll 4
        for (int c = 0; c < HID; ++c) acc += tl_s[c] * W_lattice[c * 6 + tid];
        out[(size_t)g * 6 + tid] = acc;
    }
}

extern "C" void kernel_launch(void* const* d_in, const int* in_sizes, int n_in,
                              void* d_out, int out_size, void* d_ws, size_t ws_size,
                              hipStream_t stream) {
    const float* t_in    = (const float*)d_in[0];
    const float* bb      = (const float*)d_in[1];
    const float* frac    = (const float*)d_in[2];
    const float* so3     = (const float*)d_in[3];
    const float* lat     = (const float*)d_in[4];
    // d_in[5] num_atoms, d_in[6] node2graph, d_in[7] edge_index: deterministic, unused
    const float* W_emb   = (const float*)d_in[8];
    const float* b_emb   = (const float*)d_in[9];
    const float* W_lat   = (const float*)d_in[10];
    const float* b_lat   = (const float*)d_in[11];
    const float* We1     = (const float*)d_in[12];
    const float* be1     = (const float*)d_in[13];
    const float* We2     = (const float*)d_in[14];
    const float* be2     = (const float*)d_in[15];
    const float* Wn1     = (const float*)d_in[16];
    const float* bn1     = (const float*)d_in[17];
    const float* Wn2     = (const float*)d_in[18];
    const float* bn2     = (const float*)d_in[19];
    const float* W_coord = (const float*)d_in[20];
    const float* W_latt  = (const float*)d_in[21];
    const float* W_so3   = (const float*)d_in[22];

    hipLaunchKernelGGL(cspnet_fused, dim3(NG), dim3(TPB), 0, stream,
                       t_in, bb, frac, so3, lat, W_emb, b_emb, W_lat, b_lat,
                       We1, be1, We2, be2, Wn1, bn1, Wn2, bn2,
                       W_coord, W_latt, W_so3, (float*)d_out);
}

// Round 2
// 372.890 us; speedup vs baseline: 4.9881x; 4.9881x over previous
//
#include <hip/hip_runtime.h>
#include <hip/hip_bf16.h>

// CSPNet fused forward, MI355X, MFMA version.
// One block per graph (G=512, A=24). All GEMMs via mfma_f32_16x16x32_bf16.
// Weights pre-packed to bf16 fragment layout in d_ws by pack_weights kernel.
// Edge decomposition: ein@We1 = pe@W1d + onehot@[hA_slice; hB; latc] (K=32 aug).

#define NG 512
#define NA 24
#define HID 128
#define TDIM 256
#define NBB 64
#define TPB 256
#define LFRAGS 208
#define OFF_A 0     // We1 rows 0-127   (hA weights)   32 frags
#define OFF_B 32    // We1 rows 128-255 (hB weights)   32 frags
#define OFF_D 64    // We1 rows 262-321 (pe weights, K=64 permuted) 16 frags
#define OFF_E2 80   // We2                              32 frags
#define OFF_N1 112  // Wn1 (K=256)                      64 frags
#define OFF_N2 176  // Wn2                              32 frags

typedef __bf16 bf16x8 __attribute__((ext_vector_type(8)));
typedef float  f32x4  __attribute__((ext_vector_type(4)));

// ---- LDS layout (bytes) ----
#define O_HB   0        // h bf16 [24][136]                     6528
#define O_BAUG 6528     // aug B frag buf: 8 ct * 512 u16       8192
#define O_AGG  14720    // agg bf16 [24][136]                   6528 (overflow rows -> pe, harmless)
#define O_PE   21248    // pe bf16 [96][72]; also h fp32 scratch [24][128]  13824
#define O_MID  35072    // mid bf16 [96][136]; also emb scratch, t1 buf     26112
#define O_TL   61184    // tl/gfeat fp32 [128]                  512
#define O_FRAC 61696    // frac fp32 [24][3]                    288
#define O_LAT6 61984    // lattice fp32 [6]                     24
#define SMEM_BYTES 62016

__device__ __forceinline__ float silu_f(float x) { return x / (1.0f + __expf(-x)); }

__device__ __forceinline__ unsigned short cvtbf(float x) {
    __hip_bfloat16 b = __float2bfloat16(x);
    return *reinterpret_cast<unsigned short*>(&b);
}

__device__ __forceinline__ f32x4 MFMA(bf16x8 a, bf16x8 b, f32x4 c) {
    return __builtin_amdgcn_mfma_f32_16x16x32_bf16(a, b, c, 0, 0, 0);
}

// global packed fragment: 512 u16 per frag, lane reads 16B
__device__ __forceinline__ bf16x8 gfrag(const unsigned short* ws, int fragIdx, int l) {
    const int4* p = reinterpret_cast<const int4*>(ws + (size_t)fragIdx * 512) + l;
    return __builtin_bit_cast(bf16x8, *p);
}
// LDS activation frag from row-major [row][K] bf16 buffer (stride in u16, mult of 8)
__device__ __forceinline__ bf16x8 lfrag(const unsigned short* buf, int stride, int row0, int kofs, int l) {
    const int4* p = reinterpret_cast<const int4*>(buf + (row0 + (l & 15)) * stride + kofs + ((l >> 4) << 3));
    return __builtin_bit_cast(bf16x8, *p);
}
// LDS fragment-layout buffer (Baug)
__device__ __forceinline__ bf16x8 lfragRaw(const unsigned short* buf, int fragIdx, int l) {
    const int4* p = reinterpret_cast<const int4*>(buf + fragIdx * 512) + l;
    return __builtin_bit_cast(bf16x8, *p);
}
// register-generated one-hot aug operand (B-side): Aaug[row][k], k = q*8+e
// k<4: i0local one-hot; 4..27: j one-hot; 28: const 1; 29-31: 0
__device__ __forceinline__ bf16x8 augfrag(int row, int q) {
    int i0l = row / 24;
    int ja  = row - i0l * 24;
    int k2  = 4 + ja;
    bf16x8 v;
#pragma unroll
    for (int e = 0; e < 8; ++e) {
        int k = q * 8 + e;
        bool one = (k == i0l) || (k == k2) || (k == 28);
        v[e] = one ? (__bf16)1.0f : (__bf16)0.0f;
    }
    return v;
}

#define FMA4(ACC, S, W) { (ACC).x += (S)*(W).x; (ACC).y += (S)*(W).y; \
                          (ACC).z += (S)*(W).z; (ACC).w += (S)*(W).w; }

__device__ __forceinline__ float4 ld4(const float* __restrict__ p) {
    return *reinterpret_cast<const float4*>(p);
}

// ---------------- weight packing kernel ----------------
// frag value: W[ks*32 + q*8 + j][nt*16 + (l&15)] at ws[(w*64 + l)*8 + j]
__global__ void __launch_bounds__(TPB) pack_weights(
    const float* __restrict__ We1, const float* __restrict__ We2,
    const float* __restrict__ Wn1, const float* __restrict__ Wn2,
    unsigned short* __restrict__ ws)
{
    int w = blockIdx.x * 4 + (threadIdx.x >> 6);   // 0..831
    int l = threadIdx.x & 63;
    int q = l >> 4, c16 = l & 15;
    int layer = w / LFRAGS, r = w % LFRAGS;
    const float* src; int K4, seg, klim; bool isPE = false;
    if (r < 32)       { seg = 0;   K4 = 4; src = We1 + (size_t)layer*322*128;           klim = 128; }
    else if (r < 64)  { seg = 32;  K4 = 4; src = We1 + (size_t)layer*322*128 + 128*128; klim = 128; }
    else if (r < 80)  { seg = 64;  K4 = 2; src = We1 + (size_t)layer*322*128 + 262*128; klim = 60; isPE = true; }
    else if (r < 112) { seg = 80;  K4 = 4; src = We2 + (size_t)layer*128*128;           klim = 128; }
    else if (r < 176) { seg = 112; K4 = 8; src = Wn1 + (size_t)layer*256*128;           klim = 256; }
    else              { seg = 176; K4 = 4; src = Wn2 + (size_t)layer*128*128;           klim = 128; }
    int rr = r - seg; int nt = rr / K4, ks = rr % K4;
    unsigned short vals[8];
#pragma unroll
    for (int j = 0; j < 8; ++j) {
        int row = ks * 32 + q * 8 + j;
        float v = 0.f;
        if (row < klim) {
            int srow = row;
            if (isPE) { // permuted pe layout: col' = d*20 + sc*10 + f  ->  orig = sc*30 + d*10 + f
                int d = row / 20, t = row % 20, sc = t / 10, f = t % 10;
                srow = sc * 30 + d * 10 + f;
            }
            v = src[(size_t)srow * 128 + nt * 16 + c16];
        }
        vals[j] = cvtbf(v);
    }
    unsigned int d0 = (unsigned)vals[0] | ((unsigned)vals[1] << 16);
    unsigned int d1 = (unsigned)vals[2] | ((unsigned)vals[3] << 16);
    unsigned int d2 = (unsigned)vals[4] | ((unsigned)vals[5] << 16);
    unsigned int d3 = (unsigned)vals[6] | ((unsigned)vals[7] << 16);
    int4 o = make_int4((int)d0, (int)d1, (int)d2, (int)d3);
    *reinterpret_cast<int4*>(ws + ((size_t)w * 64 + l) * 8) = o;
}

// ---------------- main fused kernel ----------------
__global__ void __launch_bounds__(TPB, 2) cspnet_mfma(
    const float* __restrict__ t_in, const float* __restrict__ bb_embs,
    const float* __restrict__ frac, const float* __restrict__ so3,
    const float* __restrict__ lattices,
    const float* __restrict__ W_emb, const float* __restrict__ b_emb,
    const float* __restrict__ W_lat, const float* __restrict__ b_lat,
    const float* __restrict__ We1, const float* __restrict__ be1,
    const float* __restrict__ be2, const float* __restrict__ bn1,
    const float* __restrict__ bn2,
    const float* __restrict__ W_coord, const float* __restrict__ W_lattice,
    const float* __restrict__ W_so3,
    const unsigned short* __restrict__ wsU,
    float* __restrict__ out)
{
    __shared__ __align__(16) char smem[SMEM_BYTES];
    unsigned short* hbU   = (unsigned short*)(smem + O_HB);
    unsigned short* baugU = (unsigned short*)(smem + O_BAUG);
    unsigned short* aggU  = (unsigned short*)(smem + O_AGG);
    unsigned short* peU   = (unsigned short*)(smem + O_PE);
    unsigned short* midU  = (unsigned short*)(smem + O_MID);
    unsigned short* t1U   = midU;
    float* tlS   = (float*)(smem + O_TL);
    float* fracS = (float*)(smem + O_FRAC);
    float* lat6S = (float*)(smem + O_LAT6);
    float* embS  = (float*)(smem + O_MID);   // prologue scratch [24][128] fp32
    float* hscrF = (float*)(smem + O_PE);    // prologue/epilogue h fp32 [24][128]

    const int g   = blockIdx.x;
    const int tid = threadIdx.x;
    const int l   = tid & 63;
    const int wv  = tid >> 6;
    const int q   = l >> 4;
    const int c16 = l & 15;
    const float inv24 = 1.0f / 24.0f;
    const f32x4 FZ = {0.f, 0.f, 0.f, 0.f};

    // ---------------- prologue ----------------
    if (tid < NA * 3) {
        int i = tid / 3, d = tid - i * 3;
        fracS[i * 3 + d] = frac[(size_t)(g * NA + i) * 3 + d];
    }
    if (tid < 6) lat6S[tid] = lattices[(size_t)g * 6 + tid];
    // zero Baug rows ka=29..31 (K-pad garbage must not be NaN)
    for (int v = tid; v < 384; v += TPB) {
        int ct = v / 48, rest = v % 48, cl = rest / 3, jp = 5 + rest % 3;
        baugU[ct * 512 + (48 + cl) * 8 + jp] = 0;
    }

    // emb = bb @ W_emb + b_emb -> embS (fp32 VALU, runs once)
    {
        const int cg = tid & 31, rg = tid >> 5, c0 = cg * 4;
        float4 acc[3];
        float4 be = ld4(b_emb + c0);
        acc[0] = be; acc[1] = be; acc[2] = be;
        const float* bbg = bb_embs + (size_t)(g * NA) * NBB;
#pragma unroll 4
        for (int k = 0; k < NBB; ++k) {
            float4 w = ld4(W_emb + (size_t)k * HID + c0);
            float b0v = bbg[rg * NBB + k];
            float b1v = bbg[(rg + 8) * NBB + k];
            float b2v = bbg[(rg + 16) * NBB + k];
            FMA4(acc[0], b0v, w); FMA4(acc[1], b1v, w); FMA4(acc[2], b2v, w);
        }
#pragma unroll
        for (int s = 0; s < 3; ++s)
            *reinterpret_cast<float4*>(&embS[(rg + 8 * s) * HID + c0]) = acc[s];
    }
    // tl[c] = sum_k t[g][k] * W_lat[144+k][c]
    if (tid < HID) {
        float acc = 0.f;
        const float* tg = t_in + (size_t)g * TDIM;
        for (int k = 0; k < TDIM; ++k)
            acc += tg[k] * W_lat[(size_t)(144 + k) * HID + tid];
        tlS[tid] = acc;
    }
    __syncthreads();

    // h = [emb | so3] @ W_lat[0:144] + tl + b_lat -> hscrF (fp32) + hbU (bf16)
    {
        const int cg = tid & 31, rg = tid >> 5, c0 = cg * 4;
        float4 acc[3];
        float4 bl = ld4(b_lat + c0);
        float4 tv = *reinterpret_cast<const float4*>(tlS + c0);
        bl.x += tv.x; bl.y += tv.y; bl.z += tv.z; bl.w += tv.w;
        acc[0] = bl; acc[1] = bl; acc[2] = bl;
#pragma unroll 4
        for (int k = 0; k < HID; ++k) {
            float4 w = ld4(W_lat + (size_t)k * HID + c0);
            float e0 = embS[rg * HID + k], e1 = embS[(rg + 8) * HID + k], e2 = embS[(rg + 16) * HID + k];
            FMA4(acc[0], e0, w); FMA4(acc[1], e1, w); FMA4(acc[2], e2, w);
        }
        const float* so3g = so3 + (size_t)(g * NA) * 16;
#pragma unroll
        for (int k = 0; k < 16; ++k) {
            float4 w = ld4(W_lat + (size_t)(HID + k) * HID + c0);
            float s0 = so3g[rg * 16 + k], s1 = so3g[(rg + 8) * 16 + k], s2 = so3g[(rg + 16) * 16 + k];
            FMA4(acc[0], s0, w); FMA4(acc[1], s1, w); FMA4(acc[2], s2, w);
        }
#pragma unroll
        for (int s = 0; s < 3; ++s) {
            int row = rg + 8 * s;
            *reinterpret_cast<float4*>(&hscrF[row * HID + c0]) = acc[s];
            ushort4 v = make_ushort4(cvtbf(acc[s].x), cvtbf(acc[s].y), cvtbf(acc[s].z), cvtbf(acc[s].w));
            *reinterpret_cast<ushort4*>(&hbU[row * 136 + c0]) = v;
        }
    }
    __syncthreads();

    // persistent fp32 h master in registers (P3 tile mapping: ct = wv*2+ctl, rt, reg)
    float hreg[2][2][4];
#pragma unroll
    for (int ctl = 0; ctl < 2; ++ctl)
#pragma unroll
        for (int rt = 0; rt < 2; ++rt) {
            int row = rt * 16 + c16;
#pragma unroll
            for (int r = 0; r < 4; ++r)
                hreg[ctl][rt][r] = (row < 24) ? hscrF[row * HID + (wv * 2 + ctl) * 16 + q * 4 + r] : 0.f;
        }
    __syncthreads();
    // zero pe K-pad cols 60..63 (must not be NaN; persists — fills touch cols 0..59 only)
    for (int v = tid; v < 384; v += TPB) {
        int row = v >> 2, c = 60 + (v & 3);
        peU[row * 72 + c] = 0;
    }

    // ---------------- layers ----------------
    for (int ly = 0; ly < 4; ++ly) {
        const int LOFF = ly * LFRAGS;
        const float* be1_l = be1 + ly * HID;
        const float* We1_l = We1 + (size_t)ly * 322 * HID;
        const float* be2_l = be2 + ly * HID;
        const float* bn1_l = bn1 + ly * HID;
        const float* bn2_l = bn2 + ly * HID;

        // per-wave resident weight fragments
        bf16x8 w1dr[4][2];
#pragma unroll
        for (int ctl = 0; ctl < 4; ++ctl)
#pragma unroll
            for (int ks = 0; ks < 2; ++ks)
                w1dr[ctl][ks] = gfrag(wsU, LOFF + OFF_D + ((wv & 1) * 4 + ctl) * 2 + ks, l);
        bf16x8 we2r[4][4];
#pragma unroll
        for (int ntl = 0; ntl < 4; ++ntl)
#pragma unroll
            for (int ks = 0; ks < 4; ++ks)
                we2r[ntl][ks] = gfrag(wsU, LOFF + OFF_E2 + ((wv & 1) * 4 + ntl) * 4 + ks, l);
        float be2r[4];
#pragma unroll
        for (int ntl = 0; ntl < 4; ++ntl)
            be2r[ntl] = be2_l[((wv & 1) * 4 + ntl) * 16 + c16];

        // P1: hB = h @ We1[128:256]  (transposed: D[c][row]) -> Baug rows ka=4+j
        {
            f32x4 pacc[2][2];
#pragma unroll
            for (int a = 0; a < 2; ++a) { pacc[a][0] = FZ; pacc[a][1] = FZ; }
#pragma unroll
            for (int ks = 0; ks < 4; ++ks) {
                bf16x8 b0 = lfrag(hbU, 136, 0, ks * 32, l);
                bf16x8 b1 = lfrag(hbU, 136, 16, ks * 32, l);
#pragma unroll
                for (int ctl = 0; ctl < 2; ++ctl) {
                    bf16x8 a = gfrag(wsU, LOFF + OFF_B + (wv * 2 + ctl) * 4 + ks, l);
                    pacc[ctl][0] = MFMA(a, b0, pacc[ctl][0]);
                    pacc[ctl][1] = MFMA(a, b1, pacc[ctl][1]);
                }
            }
#pragma unroll
            for (int ctl = 0; ctl < 2; ++ctl)
#pragma unroll
                for (int rt = 0; rt < 2; ++rt) {
                    int row = rt * 16 + c16;
                    if (row < 24) {
                        int ka = 4 + row, qp = ka >> 3, jp = ka & 7;
#pragma unroll
                        for (int r = 0; r < 4; ++r) {
                            int c = (wv * 2 + ctl) * 16 + q * 4 + r;
                            baugU[(c >> 4) * 512 + (qp * 16 + (c & 15)) * 8 + jp] = cvtbf(pacc[ctl][rt][r]);
                        }
                    }
                }
        }
        // latc = lat6 @ We1[256:262] + be1 -> Baug row ka=28
        if (tid < HID) {
            float a = be1_l[tid];
#pragma unroll
            for (int k = 0; k < 6; ++k)
                a += lat6S[k] * We1_l[(size_t)(256 + k) * HID + tid];
            int c = tid;
            baugU[(c >> 4) * 512 + (48 + (c & 15)) * 8 + 4] = cvtbf(a);
        }
        __syncthreads();   // B_top

        // -------- edge chunks: 6 chunks of 4 source atoms (96 edges) --------
        for (int ck = 0; ck < 6; ++ck) {
            // pe fill: rows = i0l*24 + j, permuted cols [sin0..9|cos0..9] at d*20
            for (int v = tid; v < 288; v += TPB) {
                int row = v / 3, d = v - row * 3;
                int i0l = row / 24, ja = row - i0l * 24;
                float fd = fracS[ja * 3 + d] - fracS[(ck * 4 + i0l) * 3 + d];
                fd -= floorf(fd);
                float sv[20];
#pragma unroll
                for (int f = 0; f < 10; ++f) {
                    float ang = fd * (6.2831853071795864f * (float)f);
                    sv[f] = __sinf(ang); sv[10 + f] = __cosf(ang);
                }
                unsigned short* dst = peU + row * 72 + d * 20;
#pragma unroll
                for (int m = 0; m < 5; ++m) {
                    ushort4 pk = make_ushort4(cvtbf(sv[m*4]), cvtbf(sv[m*4+1]), cvtbf(sv[m*4+2]), cvtbf(sv[m*4+3]));
                    *reinterpret_cast<ushort4*>(dst + m * 4) = pk;
                }
            }
            // hA slice: hA[ck*4 + p] = h @ We1[0:128] -> Baug rows ka=0..3
            {
                f32x4 hacc[2] = {FZ, FZ};
#pragma unroll
                for (int ks = 0; ks < 4; ++ks) {
                    bf16x8 b = lfrag(hbU, 136, ck * 4, ks * 32, l);
#pragma unroll
                    for (int ctl = 0; ctl < 2; ++ctl) {
                        bf16x8 a = gfrag(wsU, LOFF + OFF_A + (wv * 2 + ctl) * 4 + ks, l);
                        hacc[ctl] = MFMA(a, b, hacc[ctl]);
                    }
                }
                if (c16 < 4) {
#pragma unroll
                    for (int ctl = 0; ctl < 2; ++ctl)
#pragma unroll
                        for (int r = 0; r < 4; ++r) {
                            int c = (wv * 2 + ctl) * 16 + q * 4 + r;
                            baugU[(c >> 4) * 512 + (c & 15) * 8 + c16] = cvtbf(hacc[ctl][r]);
                        }
                }
            }
            __syncthreads();   // B_a

            // mid = silu(pe@W1d + aug) (transposed) : wave = (ct-half, rt-third)
            {
                const int ct0 = (wv & 1) * 4;
                const int rt0 = (wv >> 1) * 3;
                f32x4 macc[4][3];
#pragma unroll
                for (int a = 0; a < 4; ++a)
#pragma unroll
                    for (int b = 0; b < 3; ++b) macc[a][b] = FZ;
#pragma unroll
                for (int ks = 0; ks < 2; ++ks) {
                    bf16x8 bb[3];
#pragma unroll
                    for (int rtl = 0; rtl < 3; ++rtl)
                        bb[rtl] = lfrag(peU, 72, (rt0 + rtl) * 16, ks * 32, l);
#pragma unroll
                    for (int ctl = 0; ctl < 4; ++ctl)
#pragma unroll
                        for (int rtl = 0; rtl < 3; ++rtl)
                            macc[ctl][rtl] = MFMA(w1dr[ctl][ks], bb[rtl], macc[ctl][rtl]);
                }
                {   // aug K=32 step: A = Baug frags (LDS), B = register one-hots
                    bf16x8 ab[3];
#pragma unroll
                    for (int rtl = 0; rtl < 3; ++rtl)
                        ab[rtl] = augfrag((rt0 + rtl) * 16 + c16, q);
#pragma unroll
                    for (int ctl = 0; ctl < 4; ++ctl) {
                        bf16x8 a2 = lfragRaw(baugU, ct0 + ctl, l);
#pragma unroll
                        for (int rtl = 0; rtl < 3; ++rtl)
                            macc[ctl][rtl] = MFMA(a2, ab[rtl], macc[ctl][rtl]);
                    }
                }
#pragma unroll
                for (int ctl = 0; ctl < 4; ++ctl)
#pragma unroll
                    for (int rtl = 0; rtl < 3; ++rtl) {
                        int row = (rt0 + rtl) * 16 + c16;
                        int cb = (ct0 + ctl) * 16 + q * 4;
                        ushort4 v = make_ushort4(cvtbf(silu_f(macc[ctl][rtl][0])),
                                                 cvtbf(silu_f(macc[ctl][rtl][1])),
                                                 cvtbf(silu_f(macc[ctl][rtl][2])),
                                                 cvtbf(silu_f(macc[ctl][rtl][3])));
                        *reinterpret_cast<ushort4*>(&midU[row * 136 + cb]) = v;
                    }
            }
            __syncthreads();   // B_b

            // ef = silu(mid@We2 + be2); agg[i0] = mean_j ef  (original orientation)
            {
                const int mh = wv >> 1;
                f32x4 eacc[3][4];
#pragma unroll
                for (int a = 0; a < 3; ++a)
#pragma unroll
                    for (int b = 0; b < 4; ++b) eacc[a][b] = FZ;
#pragma unroll
                for (int mtl = 0; mtl < 3; ++mtl) {
                    bf16x8 am[4];
#pragma unroll
                    for (int ks = 0; ks < 4; ++ks)
                        am[ks] = lfrag(midU, 136, (3 * mh + mtl) * 16, ks * 32, l);
#pragma unroll
                    for (int ntl = 0; ntl < 4; ++ntl)
#pragma unroll
                        for (int ks = 0; ks < 4; ++ks)
                            eacc[mtl][ntl] = MFMA(am[ks], we2r[ntl][ks], eacc[mtl][ntl]);
                }
#pragma unroll
                for (int ntl = 0; ntl < 4; ++ntl) {
                    float s0 = 0.f, s1 = 0.f;
#pragma unroll
                    for (int r = 0; r < 4; ++r) {
                        float e0 = silu_f(eacc[0][ntl][r] + be2r[ntl]);
                        float e1 = silu_f(eacc[1][ntl][r] + be2r[ntl]);
                        float e2 = silu_f(eacc[2][ntl][r] + be2r[ntl]);
                        s0 += e0; s1 += e2;
                        if (q < 2) s0 += e1; else s1 += e1;
                    }
                    s0 += __shfl_xor(s0, 16, 64); s0 += __shfl_xor(s0, 32, 64);
                    s1 += __shfl_xor(s1, 16, 64); s1 += __shfl_xor(s1, 32, 64);
                    if (q == 0) {
                        int i0a = ck * 4 + 2 * mh;
                        int cc = ((wv & 1) * 4 + ntl) * 16 + c16;
                        aggU[i0a * 136 + cc]       = cvtbf(s0 * inv24);
                        aggU[(i0a + 1) * 136 + cc] = cvtbf(s1 * inv24);
                    }
                }
            }
            __syncthreads();   // B_c
        }

        // -------- node MLP --------
        // t1 = silu([h | agg] @ Wn1 + bn1)  (transposed)
        {
            f32x4 t1a[2][2];
#pragma unroll
            for (int a = 0; a < 2; ++a) { t1a[a][0] = FZ; t1a[a][1] = FZ; }
#pragma unroll
            for (int ks = 0; ks < 8; ++ks) {
                bf16x8 b0, b1;
                if (ks < 4) { b0 = lfrag(hbU, 136, 0, ks * 32, l);  b1 = lfrag(hbU, 136, 16, ks * 32, l); }
                else        { b0 = lfrag(aggU, 136, 0, (ks - 4) * 32, l); b1 = lfrag(aggU, 136, 16, (ks - 4) * 32, l); }
#pragma unroll
                for (int ctl = 0; ctl < 2; ++ctl) {
                    bf16x8 a = gfrag(wsU, LOFF + OFF_N1 + (wv * 2 + ctl) * 8 + ks, l);
                    t1a[ctl][0] = MFMA(a, b0, t1a[ctl][0]);
                    t1a[ctl][1] = MFMA(a, b1, t1a[ctl][1]);
                }
            }
            float bn1r[2][4];
#pragma unroll
            for (int ctl = 0; ctl < 2; ++ctl)
#pragma unroll
                for (int r = 0; r < 4; ++r)
                    bn1r[ctl][r] = bn1_l[(wv * 2 + ctl) * 16 + q * 4 + r];
#pragma unroll
            for (int ctl = 0; ctl < 2; ++ctl)
#pragma unroll
                for (int rt = 0; rt < 2; ++rt) {
                    int row = rt * 16 + c16;
                    int cb = (wv * 2 + ctl) * 16 + q * 4;
                    ushort4 v = make_ushort4(cvtbf(silu_f(t1a[ctl][rt][0] + bn1r[ctl][0])),
                                             cvtbf(silu_f(t1a[ctl][rt][1] + bn1r[ctl][1])),
                                             cvtbf(silu_f(t1a[ctl][rt][2] + bn1r[ctl][2])),
                                             cvtbf(silu_f(t1a[ctl][rt][3] + bn1r[ctl][3])));
                    *reinterpret_cast<ushort4*>(&t1U[row * 136 + cb]) = v;
                }
        }
        __syncthreads();
        // h += silu(t1 @ Wn2 + bn2)
        {
            f32x4 t2a[2][2];
#pragma unroll
            for (int a = 0; a < 2; ++a) { t2a[a][0] = FZ; t2a[a][1] = FZ; }
#pragma unroll
            for (int ks = 0; ks < 4; ++ks) {
                bf16x8 b0 = lfrag(t1U, 136, 0, ks * 32, l);
                bf16x8 b1 = lfrag(t1U, 136, 16, ks * 32, l);
#pragma unroll
                for (int ctl = 0; ctl < 2; ++ctl) {
                    bf16x8 a = gfrag(wsU, LOFF + OFF_N2 + (wv * 2 + ctl) * 4 + ks, l);
                    t2a[ctl][0] = MFMA(a, b0, t2a[ctl][0]);
                    t2a[ctl][1] = MFMA(a, b1, t2a[ctl][1]);
                }
            }
            float bn2r[2][4];
#pragma unroll
            for (int ctl = 0; ctl < 2; ++ctl)
#pragma unroll
                for (int r = 0; r < 4; ++r)
                    bn2r[ctl][r] = bn2_l[(wv * 2 + ctl) * 16 + q * 4 + r];
#pragma unroll
            for (int ctl = 0; ctl < 2; ++ctl)
#pragma unroll
                for (int rt = 0; rt < 2; ++rt) {
                    int row = rt * 16 + c16;
#pragma unroll
                    for (int r = 0; r < 4; ++r)
                        hreg[ctl][rt][r] += silu_f(t2a[ctl][rt][r] + bn2r[ctl][r]);
                    if (row < 24) {
                        int cb = (wv * 2 + ctl) * 16 + q * 4;
                        ushort4 v = make_ushort4(cvtbf(hreg[ctl][rt][0]), cvtbf(hreg[ctl][rt][1]),
                                                 cvtbf(hreg[ctl][rt][2]), cvtbf(hreg[ctl][rt][3]));
                        *reinterpret_cast<ushort4*>(&hbU[row * 136 + cb]) = v;
                    }
                }
        }
        __syncthreads();
    }

    // ---------------- epilogue ----------------
    // dump h fp32 -> hscrF
#pragma unroll
    for (int ctl = 0; ctl < 2; ++ctl)
#pragma unroll
        for (int rt = 0; rt < 2; ++rt) {
            int row = rt * 16 + c16;
            if (row < 24) {
                float4 v = make_float4(hreg[ctl][rt][0], hreg[ctl][rt][1], hreg[ctl][rt][2], hreg[ctl][rt][3]);
                *reinterpret_cast<float4*>(&hscrF[row * HID + (wv * 2 + ctl) * 16 + q * 4]) = v;
            }
        }
    __syncthreads();

    if (tid < HID) {
        float s = 0.f;
#pragma unroll 4
        for (int i = 0; i < NA; ++i) s += hscrF[i * HID + tid];
        tlS[tid] = s * inv24;
    }
    if (tid < NA * 3) {
        int i = tid / 3, d = tid - i * 3;
        float acc = 0.f;
#pragma unroll 4
        for (int k = 0; k < HID; ++k) acc += hscrF[i * HID + k] * W_coord[k * 3 + d];
        acc += fracS[i * 3 + d];
        acc -= floorf(acc);
        out[(size_t)NG * 6 + (size_t)(g * NA + i) * 3 + d] = acc;
    }
    if (tid < NA) {
        int i = tid;
        float v0 = 0.f, v1 = 0.f, v2 = 0.f, v3 = 0.f;
#pragma unroll 4
        for (int k = 0; k < HID; ++k) {
            float hv = hscrF[i * HID + k];
            v0 += hv * W_so3[k * 4 + 0]; v1 += hv * W_so3[k * 4 + 1];
            v2 += hv * W_so3[k * 4 + 2]; v3 += hv * W_so3[k * 4 + 3];
        }
        float inv = 1.0f / sqrtf(v0 * v0 + v1 * v1 + v2 * v2 + v3 * v3);
        size_t o = (size_t)NG * 6 + (size_t)NG * NA * 3 + (size_t)(g * NA + i) * 4;
        out[o + 0] = v0 * inv; out[o + 1] = v1 * inv;
        out[o + 2] = v2 * inv; out[o + 3] = v3 * inv;
    }
    __syncthreads();
    if (tid < 6) {
        float acc = 0.f;
#pragma unroll 4
        for (int c = 0; c < HID; ++c) acc += tlS[c] * W_lattice[c * 6 + tid];
        out[(size_t)g * 6 + tid] = acc;
    }
}

extern "C" void kernel_launch(void* const* d_in, const int* in_sizes, int n_in,
                              void* d_out, int out_size, void* d_ws, size_t ws_size,
                              hipStream_t stream) {
    const float* t_in    = (const float*)d_in[0];
    const float* bb      = (const float*)d_in[1];
    const float* frac    = (const float*)d_in[2];
    const float* so3     = (const float*)d_in[3];
    const float* lat     = (const float*)d_in[4];
    const float* W_emb   = (const float*)d_in[8];
    const float* b_emb   = (const float*)d_in[9];
    const float* W_lat   = (const float*)d_in[10];
    const float* b_lat   = (const float*)d_in[11];
    const float* We1     = (const float*)d_in[12];
    const float* be1     = (const float*)d_in[13];
    const float* We2     = (const float*)d_in[14];
    const float* be2     = (const float*)d_in[15];
    const float* Wn1     = (const float*)d_in[16];
    const float* bn1     = (const float*)d_in[17];
    const float* Wn2     = (const float*)d_in[18];
    const float* bn2     = (const float*)d_in[19];
    const float* W_coord = (const float*)d_in[20];
    const float* W_latt  = (const float*)d_in[21];
    const float* W_so3   = (const float*)d_in[22];

    unsigned short* ws = (unsigned short*)d_ws;
    hipLaunchKernelGGL(pack_weights, dim3(208), dim3(TPB), 0, stream,
                       We1, We2, Wn1, Wn2, ws);
    hipLaunchKernelGGL(cspnet_mfma, dim3(NG), dim3(TPB), 0, stream,
                       t_in, bb, frac, so3, lat, W_emb, b_emb, W_lat, b_lat,
                       We1, be1, be2, bn1, bn2, W_coord, W_latt, W_so3,
                       (const unsigned short*)ws, (float*)d_out);
}